// Round 26
// baseline (632.879 us; speedup 1.0000x reference)
//
#include <hip/hip_runtime.h>

typedef __bf16 bf16x8 __attribute__((ext_vector_type(8)));
typedef float f32x4 __attribute__((ext_vector_type(4)));
typedef float f32x16 __attribute__((ext_vector_type(16)));
typedef unsigned short u16;
typedef unsigned int u32;
typedef u16 u16x8 __attribute__((ext_vector_type(8)));
typedef u16 u16x4 __attribute__((ext_vector_type(4)));
typedef u32 u32x4 __attribute__((ext_vector_type(4)));

#define B_ 2
#define S_ 2048
#define D_ 4096
#define H_ 32
#define HD_ 128
#define SM_SCALE 0.08838834764831845f   // 1/sqrt(128)
#define C2_ 0.12751743f                 // SM_SCALE * log2(e)
#define THR_ 8.1611155f                 // 64 * C2_ (defer-max threshold, scaled units)

__device__ __forceinline__ u16 f2bf(float f) {
  __bf16 h = (__bf16)f;
  return __builtin_bit_cast(unsigned short, h);
}
__device__ __forceinline__ float bf2f(u16 u) {
  return (float)__builtin_bit_cast(__bf16, u);
}

// async global->LDS, 16B per lane. LDS dest must be wave-uniform base + lane*16.
#define GLD_TO_LDS16(gsrc, ldst)                                                     \
  __builtin_amdgcn_global_load_lds((__attribute__((address_space(1))) void*)(gsrc),  \
                                   (__attribute__((address_space(3))) void*)(ldst),  \
                                   16, 0, 0)

// ---------------- fp32 -> bf16 conversion, 5 tensors, 16B stores ----------------
// v22: 8 floats/thread/iter — two float4 loads (32B) + one u16x8 store (16B).
// 16B stores are the coalescing sweet spot (G13); r25 profiled cvt5 at only
// ~3.7 TB/s with 8B stores.
__global__ __launch_bounds__(256) void cvt5_kernel(const float* __restrict__ s0,
                                                   const float* __restrict__ s1,
                                                   const float* __restrict__ s2,
                                                   const float* __restrict__ s3,
                                                   const float* __restrict__ s4,
                                                   u16* __restrict__ d0,
                                                   u16* __restrict__ d1,
                                                   u16* __restrict__ d2,
                                                   u16* __restrict__ d3,
                                                   u16* __restrict__ d4,
                                                   int n8) {
  const int region = blockIdx.x >> 9;           // 512 blocks per tensor
  const float* src = region == 0 ? s0 : region == 1 ? s1 : region == 2 ? s2
                   : region == 3 ? s3 : s4;
  u16* dst = region == 0 ? d0 : region == 1 ? d1 : region == 2 ? d2
           : region == 3 ? d3 : d4;
  int i = (blockIdx.x & 511) * 256 + threadIdx.x;
  const int stride = 512 * 256;
  for (; i < n8; i += stride) {
    float4 v0 = reinterpret_cast<const float4*>(src)[2 * i];
    float4 v1 = reinterpret_cast<const float4*>(src)[2 * i + 1];
    u16x8 o;
    o[0] = f2bf(v0.x); o[1] = f2bf(v0.y); o[2] = f2bf(v0.z); o[3] = f2bf(v0.w);
    o[4] = f2bf(v1.x); o[5] = f2bf(v1.y); o[6] = f2bf(v1.z); o[7] = f2bf(v1.w);
    reinterpret_cast<u16x8*>(dst)[i] = o;
  }
}

// ---------------- GEMM v14b: m201-style 8-phase wheel, NO setprio ----------------
// r24-verified: setprio removed from MFMA clusters (m190: negative on lockstep).
#define LGKM0()                                            \
  do {                                                     \
    asm volatile("s_waitcnt lgkmcnt(0)" ::: "memory");     \
    __builtin_amdgcn_sched_barrier(0);                     \
  } while (0)

__device__ __forceinline__ void fill_aq(bf16x8 (&dst)[2][4], const u16* half_base,
                                        int wr, int lane) {
#pragma unroll
  for (int ks = 0; ks < 2; ++ks)
#pragma unroll
    for (int m = 0; m < 4; ++m) {
      int rr = wr * 64 + m * 16 + (lane & 15);
      int c8 = (ks * 4 + (lane >> 4)) ^ (rr & 7);
      dst[ks][m] = *reinterpret_cast<const bf16x8*>(half_base + rr * 64 + c8 * 8);
    }
}
__device__ __forceinline__ void fill_bq(bf16x8 (&dst)[2][2], const u16* half_base,
                                        int wn, int lane) {
#pragma unroll
  for (int ks = 0; ks < 2; ++ks)
#pragma unroll
    for (int n = 0; n < 2; ++n) {
      int rr = wn * 32 + n * 16 + (lane & 15);
      int c8 = (ks * 4 + (lane >> 4)) ^ (rr & 7);
      dst[ks][n] = *reinterpret_cast<const bf16x8*>(half_base + rr * 64 + c8 * 8);
    }
}

#define MFMA16(MQ, NQ, AF, BF)                                                   \
  do {                                                                           \
    _Pragma("unroll") for (int ks = 0; ks < 2; ++ks)                             \
      _Pragma("unroll") for (int m = 0; m < 4; ++m)                              \
        _Pragma("unroll") for (int n = 0; n < 2; ++n)                            \
          acc[(MQ) * 4 + m][(NQ) * 2 + n] =                                      \
              __builtin_amdgcn_mfma_f32_16x16x32_bf16(                           \
                  (AF)[ks][m], (BF)[ks][n], acc[(MQ) * 4 + m][(NQ) * 2 + n],     \
                  0, 0, 0);                                                      \
  } while (0)

template <typename OutT, bool ROPE>
__global__ __launch_bounds__(512, 2) void gemm256_kernel(const u16* __restrict__ A,
                                                         const u16* __restrict__ Bw,
                                                         OutT* __restrict__ C,
                                                         int M, int N, int K,
                                                         const float* __restrict__ fc,
                                                         const float* __restrict__ fs) {
  __shared__ u16 As[2][2][8192];  // [dbuf][half][r*64 + c]
  __shared__ u16 Bs[2][2][8192];
  const int tid = threadIdx.x;
  const int lane = tid & 63;
  const int w = tid >> 6;   // 0..7
  const int wr = w >> 2;    // 0..1
  const int wn = w & 3;     // 0..3
  const int nbx = N >> 8;
  const int nby = M >> 8;
  const int nwg = nby * nbx;
  int tr, tc;
  if (nby == 16 && nbx == 16) {
    // 4x8 rectangular chunk per XCD: L2 temporal sharing, less over-fetch
    int xcd = blockIdx.x & 7, j = blockIdx.x >> 3;
    tr = (xcd >> 1) * 4 + (j >> 3);
    tc = (xcd & 1) * 8 + (j & 7);
  } else {
    int wg = blockIdx.x;
    if ((nwg & 7) == 0) wg = (wg & 7) * (nwg >> 3) + (wg >> 3);
    tr = wg / nbx; tc = wg % nbx;
  }

  const size_t arow0 = (size_t)tr * 256;
  const size_t brow0 = (size_t)tc * 256;
  const int KT = K >> 6;

  auto stageA = [&](int t, int half) {
    if (t >= KT) return;
    const int k0 = t << 6;
    u16* base = &As[t & 1][half][0];
#pragma unroll
    for (int i = 0; i < 2; ++i) {
      int q = i * 512 + tid;
      int r = q >> 3;
      int c8 = (q & 7) ^ (r & 7);
      GLD_TO_LDS16(A + (arow0 + half * 128 + r) * K + k0 + c8 * 8, base + q * 8);
    }
  };
  auto stageB = [&](int t, int half) {
    if (t >= KT) return;
    const int k0 = t << 6;
    u16* base = &Bs[t & 1][half][0];
#pragma unroll
    for (int i = 0; i < 2; ++i) {
      int q = i * 512 + tid;
      int r = q >> 3;
      int c8 = (q & 7) ^ (r & 7);
      GLD_TO_LDS16(Bw + (brow0 + half * 128 + r) * K + k0 + c8 * 8, base + q * 8);
    }
  };

  f32x4 acc[8][4] = {};
  bf16x8 aF[2][4], bF0[2][2], bF1[2][2];

  // ---- prologue: tile0 all 4 half-tiles + tile1 {A-h0, B-h0} (12 gl_lds);
  // vmcnt(4) drains tile0 (8), leaves tile1's h0 pair in flight.
  stageA(0, 0); stageB(0, 0); stageA(0, 1); stageB(0, 1);
  stageA(1, 0); stageB(1, 0);
  asm volatile("s_waitcnt vmcnt(4)" ::: "memory");
  __builtin_amdgcn_s_barrier();
  __builtin_amdgcn_sched_barrier(0);

  for (int t = 0; t < KT; ++t) {
    const int buf = t & 1;
    const u16* Ah0 = &As[buf][0][0];
    const u16* Ah1 = &As[buf][1][0];
    const u16* Bh0 = &Bs[buf][0][0];
    const u16* Bh1 = &Bs[buf][1][0];

    // ---- P1: (0,0) — reads A-mq0 + B-nq0; stage A(t+1)h1 ----
    fill_aq(aF, Ah0, wr, lane);
    fill_bq(bF0, Bh0, wn, lane);
    stageA(t + 1, 1);
    __builtin_amdgcn_s_barrier();
    LGKM0();
    MFMA16(0, 0, aF, bF0);
    __builtin_amdgcn_s_barrier();

    // ---- P2: (0,1) — reads B-nq1; stage B(t+1)h1 ----
    fill_bq(bF1, Bh1, wn, lane);
    stageB(t + 1, 1);
    __builtin_amdgcn_s_barrier();
    LGKM0();
    MFMA16(0, 1, aF, bF1);
    __builtin_amdgcn_s_barrier();

    // ---- P3: (1,0) — reads A-mq1; stage A(t+2)h0 ----
    fill_aq(aF, Ah1, wr, lane);
    stageA(t + 2, 0);
    __builtin_amdgcn_s_barrier();
    LGKM0();
    MFMA16(1, 0, aF, bF0);
    __builtin_amdgcn_s_barrier();

    // ---- P4: (1,1) — no reads; stage B(t+2)h0; counted vmcnt ----
    stageB(t + 2, 0);
    if (t >= KT - 2) asm volatile("s_waitcnt vmcnt(0)" ::: "memory");
    else             asm volatile("s_waitcnt vmcnt(4)" ::: "memory");
    __builtin_amdgcn_s_barrier();
    __builtin_amdgcn_sched_barrier(0);
    MFMA16(1, 1, aF, bF1);
    __builtin_amdgcn_s_barrier();
  }

  // ---- epilogue (optional fused RoPE for Q/K projections) ----
#pragma unroll
  for (int mi = 0; mi < 8; ++mi) {
    const int mq = mi >> 2, m = mi & 3;
#pragma unroll
    for (int ni = 0; ni < 4; ++ni) {
      const int nq = ni >> 1, n = ni & 1;
#pragma unroll
      for (int r = 0; r < 4; ++r) {
        size_t row = arow0 + mq * 128 + wr * 64 + m * 16 + ((lane >> 4) << 2) + r;
        size_t col = (size_t)tc * 256 + nq * 128 + wn * 32 + n * 16 + (lane & 15);
        float v = acc[mi][ni][r];
        if constexpr (ROPE) {
          float o = __shfl_xor(v, 1);                       // partner (col^1), same row
          int s = (int)(row & (S_ - 1));
          int p = (wn * 32 + n * 16 + (lane & 14)) >> 1;    // (col&127)>>1
          float cv = fc[(s << 6) + p];
          float sv = fs[(s << 6) + p];
          v = (lane & 1) ? (v * cv + o * sv) : (v * cv - o * sv);
        }
        if constexpr (__is_same(OutT, float)) {
          C[row * N + col] = v;
        } else {
          C[row * N + col] = f2bf(v);
        }
      }
    }
  }
}

// ---------------- Flash attention v9 (causal): uniform-work, NO setprio ----------
// r25-verified (134 us): 256 blocks, complementary q-supertiles (uniform 36
// kv-tiles), KVB=64, swapped-operand 32x32 MFMA, in-register softmax with
// prescaled Q, tree reductions, defer-max, no setprio.
__global__ __launch_bounds__(512, 2) void attn_kernel(const u16* __restrict__ Q,
                                                      const u16* __restrict__ K,
                                                      const u16* __restrict__ V,
                                                      u16* __restrict__ O) {
  __shared__ u16 Ks[2][64 * 128];   // [kv][d], chunk-XOR swizzled (cc ^= row&7)
  __shared__ u16 Vt[2][128 * 64];   // [d][kv], chunk-XOR swizzled (kvchunk ^= d&7)

  const int blk = blockIdx.x;
  const int pr = blk >> 6;          // 0..3 (complementary pair index)
  const int bh = blk & 63;
  const int b = bh >> 5, h = bh & 31;
  const int tid = threadIdx.x, lane = tid & 63, w = tid >> 6;
  const int l31 = lane & 31;
  const int hi = lane >> 5;               // 0/1 k-half
  const int r0 = lane >> 1;               // 0..31
  const int dc = 2 * w + (lane & 1);      // 0..15
  const int vd0 = dc * 8;

  for (int ph = 0; ph < 2; ++ph) {
    const int qt = ph == 0 ? 7 - pr : pr;   // pair sums to 36 tiles
    const int q0 = qt << 8;                 // 256 q-rows per phase
    const int wq0 = q0 + w * 32;
    const int qg = wq0 + l31;               // this lane's q row

    // Q frags, prescaled by C2_ (softmax scale folded in; one extra bf16 rounding)
    bf16x8 qf[8];
#pragma unroll
    for (int kb = 0; kb < 8; ++kb) {
      u16x8 qr = *reinterpret_cast<const u16x8*>(Q + (size_t)(b * S_ + qg) * D_ + h * HD_ + kb * 16 + hi * 8);
      u16x8 qs;
#pragma unroll
      for (int j = 0; j < 8; ++j) qs[j] = f2bf(bf2f(qr[j]) * C2_);
      qf[kb] = __builtin_bit_cast(bf16x8, qs);
    }

    f32x16 oacc[4] = {};   // O^T[dblock]: col=q(lane), row=d
    float mrun = -__builtin_inff(), lrun = 0.f;

    const int ntiles = 4 * qt + 4;
    u16x8 vr0, vr1;

    {
#pragma unroll
      for (int it = 0; it < 2; ++it) {
        int ff = it * 512 + tid;
        int row = ff >> 4, cc = ff & 15;
        int scc = cc ^ (row & 7);
        GLD_TO_LDS16(K + (size_t)(b * S_ + row) * D_ + h * HD_ + scc * 8, &Ks[0][ff << 3]);
      }
      vr0 = *reinterpret_cast<const u16x8*>(V + (size_t)(b * S_ + 2 * r0) * D_ + h * HD_ + vd0);
      vr1 = *reinterpret_cast<const u16x8*>(V + (size_t)(b * S_ + 2 * r0 + 1) * D_ + h * HD_ + vd0);
      u32* vt32 = reinterpret_cast<u32*>(&Vt[0][0]);
#pragma unroll
      for (int j = 0; j < 8; ++j) {
        int d = vd0 + j;
        u32 val = (u32)vr0[j] | ((u32)vr1[j] << 16);
        vt32[d * 32 + ((r0 >> 2) ^ j) * 4 + (r0 & 3)] = val;
      }
    }
    __syncthreads();

    for (int t = 0; t < ntiles; ++t) {
      const int cur = t & 1, nxt = cur ^ 1;
      const bool pre = (t + 1 < ntiles);
      if (pre) {
        const int kv1 = (t + 1) << 6;
#pragma unroll
        for (int it = 0; it < 2; ++it) {
          int ff = it * 512 + tid;
          int row = ff >> 4, cc = ff & 15;
          int scc = cc ^ (row & 7);
          GLD_TO_LDS16(K + (size_t)(b * S_ + kv1 + row) * D_ + h * HD_ + scc * 8, &Ks[nxt][ff << 3]);
        }
        vr0 = *reinterpret_cast<const u16x8*>(V + (size_t)(b * S_ + kv1 + 2 * r0) * D_ + h * HD_ + vd0);
        vr1 = *reinterpret_cast<const u16x8*>(V + (size_t)(b * S_ + kv1 + 2 * r0 + 1) * D_ + h * HD_ + vd0);
      }

      const int kv0 = t << 6;
      if (kv0 <= wq0 + 31) {  // wave-uniform causal skip
        f32x16 st[2] = {};
#pragma unroll
        for (int kvh = 0; kvh < 2; ++kvh) {
#pragma unroll
          for (int kb = 0; kb < 8; ++kb) {
            int row = kvh * 32 + l31;
            int cc = (2 * kb + hi) ^ (row & 7);
            bf16x8 kf = *reinterpret_cast<const bf16x8*>(&Ks[cur][(row << 7) + (cc << 3)]);
            st[kvh] = __builtin_amdgcn_mfma_f32_32x32x16_bf16(kf, qf[kb], st[kvh], 0, 0, 0);
          }
        }

        if (kv0 + 63 > wq0) {
#pragma unroll
          for (int kvh = 0; kvh < 2; ++kvh)
#pragma unroll
            for (int r = 0; r < 16; ++r) {
              int kvg = kv0 + kvh * 32 + (r & 3) + 8 * (r >> 2) + 4 * hi;
              if (kvg > qg) st[kvh][r] = -1e30f;
            }
        }

        // ---- tree max over 32 lane-local values + cross-half exchange ----
        float mx[8];
#pragma unroll
        for (int i = 0; i < 8; ++i)
          mx[i] = fmaxf(fmaxf(st[0][i], st[0][i + 8]), fmaxf(st[1][i], st[1][i + 8]));
#pragma unroll
        for (int i = 0; i < 4; ++i) mx[i] = fmaxf(mx[i], mx[i + 4]);
        float vmax = fmaxf(fmaxf(mx[0], mx[1]), fmaxf(mx[2], mx[3]));
        vmax = fmaxf(vmax, __shfl_xor(vmax, 32));
        // defer-max: rescale only when some row's max grew by > THR_ (scaled units)
        if (!__all(vmax <= mrun + THR_)) {
          float mnew = fmaxf(mrun, vmax);
          float sc = exp2f(mrun - mnew);
          mrun = mnew;
          lrun *= sc;
#pragma unroll
          for (int db = 0; db < 4; ++db)
#pragma unroll
            for (int r = 0; r < 16; ++r) oacc[db][r] *= sc;
        }
        // ---- exp (arg already scaled) + tree sum ----
        float ps[8];
#pragma unroll
        for (int kvh = 0; kvh < 2; ++kvh)
#pragma unroll
          for (int r = 0; r < 16; ++r) st[kvh][r] = exp2f(st[kvh][r] - mrun);
#pragma unroll
        for (int i = 0; i < 8; ++i)
          ps[i] = (st[0][i] + st[0][i + 8]) + (st[1][i] + st[1][i + 8]);
#pragma unroll
        for (int i = 0; i < 4; ++i) ps[i] += ps[i + 4];
        float psum = (ps[0] + ps[1]) + (ps[2] + ps[3]);
        psum += __shfl_xor(psum, 32);
        lrun += psum;

#pragma unroll
        for (int h2 = 0; h2 < 2; ++h2)
#pragma unroll
          for (int s2 = 0; s2 < 2; ++s2) {
            const int rb = s2 * 8;
            u32 w0, w1, w2, w3;
            asm("v_cvt_pk_bf16_f32 %0, %1, %2" : "=v"(w0) : "v"(st[h2][rb + 0]), "v"(st[h2][rb + 1]));
            asm("v_cvt_pk_bf16_f32 %0, %1, %2" : "=v"(w1) : "v"(st[h2][rb + 2]), "v"(st[h2][rb + 3]));
            asm("v_cvt_pk_bf16_f32 %0, %1, %2" : "=v"(w2) : "v"(st[h2][rb + 4]), "v"(st[h2][rb + 5]));
            asm("v_cvt_pk_bf16_f32 %0, %1, %2" : "=v"(w3) : "v"(st[h2][rb + 6]), "v"(st[h2][rb + 7]));
            u32 sw0 = (u32)__shfl_xor((int)w0, 32);
            u32 sw1 = (u32)__shfl_xor((int)w1, 32);
            u32 sw2 = (u32)__shfl_xor((int)w2, 32);
            u32 sw3 = (u32)__shfl_xor((int)w3, 32);
            u32x4 fw;
            fw[0] = hi ? sw2 : w0;
            fw[1] = hi ? sw3 : w1;
            fw[2] = hi ? w2 : sw0;
            fw[3] = hi ? w3 : sw1;
            bf16x8 pfrag = __builtin_bit_cast(bf16x8, fw);
#pragma unroll
            for (int db = 0; db < 4; ++db) {
              int d = db * 32 + l31;
              int cc = (h2 * 4 + s2 * 2 + hi) ^ (d & 7);
              bf16x8 va = *reinterpret_cast<const bf16x8*>(&Vt[cur][(d << 6) + (cc << 3)]);
              oacc[db] = __builtin_amdgcn_mfma_f32_32x32x16_bf16(va, pfrag, oacc[db], 0, 0, 0);
            }
          }
      }

      if (pre) {
        u32* vt32 = reinterpret_cast<u32*>(&Vt[nxt][0]);
#pragma unroll
        for (int j = 0; j < 8; ++j) {
          int d = vd0 + j;
          u32 val = (u32)vr0[j] | ((u32)vr1[j] << 16);
          vt32[d * 32 + ((r0 >> 2) ^ j) * 4 + (r0 & 3)] = val;
        }
      }
      __syncthreads();
    }

    // ---- phase epilogue: O[q][d] = oacc^T / lrun ----
    const float rinv = 1.0f / lrun;
#pragma unroll
    for (int db = 0; db < 4; ++db)
#pragma unroll
      for (int g = 0; g < 4; ++g) {
        u16x4 o4;
#pragma unroll
        for (int j = 0; j < 4; ++j) o4[j] = f2bf(oacc[db][g * 4 + j] * rinv);
        int d = db * 32 + g * 8 + 4 * hi;
        *reinterpret_cast<u16x4*>(O + (size_t)(b * S_ + qg) * D_ + h * HD_ + d) = o4;
      }
  }
}

// ---------------- launcher ----------------
extern "C" void kernel_launch(void* const* d_in, const int* in_sizes, int n_in,
                              void* d_out, int out_size, void* d_ws, size_t ws_size,
                              hipStream_t stream) {
  const float* x = (const float*)d_in[0];
  const float* wq = (const float*)d_in[1];
  const float* wk = (const float*)d_in[2];
  const float* wv = (const float*)d_in[3];
  const float* wo = (const float*)d_in[4];
  const float* fc = (const float*)d_in[5];
  const float* fs = (const float*)d_in[6];
  float* out = (float*)d_out;

  const size_t SLOT = (size_t)B_ * S_ * D_;  // 16,777,216 elements
  u16* ws = (u16*)d_ws;
  u16* wqb = ws + 0 * SLOT;
  u16* wkb = ws + 1 * SLOT;
  u16* wvb = ws + 2 * SLOT;
  u16* wob = ws + 3 * SLOT;
  u16* xb  = ws + 4 * SLOT;  // reused as attention output O after QKV GEMMs
  u16* Qb  = ws + 5 * SLOT;
  u16* Kb  = ws + 6 * SLOT;
  u16* Vb  = ws + 7 * SLOT;
  u16* Ob  = xb;

  const int n8 = (int)(SLOT / 8);
  cvt5_kernel<<<2560, 256, 0, stream>>>(x, wq, wk, wv, wo, xb, wqb, wkb, wvb, wob, n8);

  gemm256_kernel<u16, true><<<256, 512, 0, stream>>>(xb, wqb, Qb, B_ * S_, D_, D_, fc, fs);
  gemm256_kernel<u16, true><<<256, 512, 0, stream>>>(xb, wkb, Kb, B_ * S_, D_, D_, fc, fs);
  gemm256_kernel<u16, false><<<256, 512, 0, stream>>>(xb, wvb, Vb, B_ * S_, D_, D_, fc, fs);

  attn_kernel<<<256, 512, 0, stream>>>(Qb, Kb, Vb, Ob);

  gemm256_kernel<float, false><<<256, 512, 0, stream>>>(Ob, wob, out, B_ * S_, D_, D_, fc, fs);
}

// Round 27
// 628.420 us; speedup vs baseline: 1.0071x; 1.0071x over previous
//
#include <hip/hip_runtime.h>

typedef __bf16 bf16x8 __attribute__((ext_vector_type(8)));
typedef float f32x4 __attribute__((ext_vector_type(4)));
typedef float f32x16 __attribute__((ext_vector_type(16)));
typedef unsigned short u16;
typedef unsigned int u32;
typedef u16 u16x8 __attribute__((ext_vector_type(8)));
typedef u16 u16x4 __attribute__((ext_vector_type(4)));
typedef u32 u32x4 __attribute__((ext_vector_type(4)));

#define B_ 2
#define S_ 2048
#define D_ 4096
#define H_ 32
#define HD_ 128
#define SM_SCALE 0.08838834764831845f   // 1/sqrt(128)
#define C2_ 0.12751743f                 // SM_SCALE * log2(e)
#define THR_ 8.1611155f                 // 64 * C2_ (defer-max threshold, scaled units)

__device__ __forceinline__ u16 f2bf(float f) {
  __bf16 h = (__bf16)f;
  return __builtin_bit_cast(unsigned short, h);
}
__device__ __forceinline__ float bf2f(u16 u) {
  return (float)__builtin_bit_cast(__bf16, u);
}

// async global->LDS, 16B per lane. LDS dest must be wave-uniform base + lane*16.
#define GLD_TO_LDS16(gsrc, ldst)                                                     \
  __builtin_amdgcn_global_load_lds((__attribute__((address_space(1))) void*)(gsrc),  \
                                   (__attribute__((address_space(3))) void*)(ldst),  \
                                   16, 0, 0)

// ---------------- fp32 -> bf16 conversion, 5 tensors in one launch ----------------
// r25-verified configuration (best total 630.6 us).
__global__ __launch_bounds__(256) void cvt5_kernel(const float* __restrict__ s0,
                                                   const float* __restrict__ s1,
                                                   const float* __restrict__ s2,
                                                   const float* __restrict__ s3,
                                                   const float* __restrict__ s4,
                                                   u16* __restrict__ d0,
                                                   u16* __restrict__ d1,
                                                   u16* __restrict__ d2,
                                                   u16* __restrict__ d3,
                                                   u16* __restrict__ d4,
                                                   int n4) {
  const int region = blockIdx.x >> 9;           // 512 blocks per tensor
  const float* src = region == 0 ? s0 : region == 1 ? s1 : region == 2 ? s2
                   : region == 3 ? s3 : s4;
  u16* dst = region == 0 ? d0 : region == 1 ? d1 : region == 2 ? d2
           : region == 3 ? d3 : d4;
  int i = (blockIdx.x & 511) * 256 + threadIdx.x;
  const int stride = 512 * 256;
  for (; i < n4; i += stride) {
    float4 v = reinterpret_cast<const float4*>(src)[i];
    u16x4 o;
    o[0] = f2bf(v.x); o[1] = f2bf(v.y); o[2] = f2bf(v.z); o[3] = f2bf(v.w);
    reinterpret_cast<u16x4*>(dst)[i] = o;
  }
}

// ---------------- GEMM v14b: m201-style 8-phase wheel, NO setprio ----------------
// r24-verified: setprio removed from MFMA clusters (m190: negative on lockstep).
#define LGKM0()                                            \
  do {                                                     \
    asm volatile("s_waitcnt lgkmcnt(0)" ::: "memory");     \
    __builtin_amdgcn_sched_barrier(0);                     \
  } while (0)

__device__ __forceinline__ void fill_aq(bf16x8 (&dst)[2][4], const u16* half_base,
                                        int wr, int lane) {
#pragma unroll
  for (int ks = 0; ks < 2; ++ks)
#pragma unroll
    for (int m = 0; m < 4; ++m) {
      int rr = wr * 64 + m * 16 + (lane & 15);
      int c8 = (ks * 4 + (lane >> 4)) ^ (rr & 7);
      dst[ks][m] = *reinterpret_cast<const bf16x8*>(half_base + rr * 64 + c8 * 8);
    }
}
__device__ __forceinline__ void fill_bq(bf16x8 (&dst)[2][2], const u16* half_base,
                                        int wn, int lane) {
#pragma unroll
  for (int ks = 0; ks < 2; ++ks)
#pragma unroll
    for (int n = 0; n < 2; ++n) {
      int rr = wn * 32 + n * 16 + (lane & 15);
      int c8 = (ks * 4 + (lane >> 4)) ^ (rr & 7);
      dst[ks][n] = *reinterpret_cast<const bf16x8*>(half_base + rr * 64 + c8 * 8);
    }
}

#define MFMA16(MQ, NQ, AF, BF)                                                   \
  do {                                                                           \
    _Pragma("unroll") for (int ks = 0; ks < 2; ++ks)                             \
      _Pragma("unroll") for (int m = 0; m < 4; ++m)                              \
        _Pragma("unroll") for (int n = 0; n < 2; ++n)                            \
          acc[(MQ) * 4 + m][(NQ) * 2 + n] =                                      \
              __builtin_amdgcn_mfma_f32_16x16x32_bf16(                           \
                  (AF)[ks][m], (BF)[ks][n], acc[(MQ) * 4 + m][(NQ) * 2 + n],     \
                  0, 0, 0);                                                      \
  } while (0)

template <typename OutT, bool ROPE>
__global__ __launch_bounds__(512, 2) void gemm256_kernel(const u16* __restrict__ A,
                                                         const u16* __restrict__ Bw,
                                                         OutT* __restrict__ C,
                                                         int M, int N, int K,
                                                         const float* __restrict__ fc,
                                                         const float* __restrict__ fs) {
  __shared__ u16 As[2][2][8192];  // [dbuf][half][r*64 + c]
  __shared__ u16 Bs[2][2][8192];
  const int tid = threadIdx.x;
  const int lane = tid & 63;
  const int w = tid >> 6;   // 0..7
  const int wr = w >> 2;    // 0..1
  const int wn = w & 3;     // 0..3
  const int nbx = N >> 8;
  const int nby = M >> 8;
  const int nwg = nby * nbx;
  int tr, tc;
  if (nby == 16 && nbx == 16) {
    // 4x8 rectangular chunk per XCD: L2 temporal sharing, less over-fetch
    int xcd = blockIdx.x & 7, j = blockIdx.x >> 3;
    tr = (xcd >> 1) * 4 + (j >> 3);
    tc = (xcd & 1) * 8 + (j & 7);
  } else {
    int wg = blockIdx.x;
    if ((nwg & 7) == 0) wg = (wg & 7) * (nwg >> 3) + (wg >> 3);
    tr = wg / nbx; tc = wg % nbx;
  }

  const size_t arow0 = (size_t)tr * 256;
  const size_t brow0 = (size_t)tc * 256;
  const int KT = K >> 6;

  auto stageA = [&](int t, int half) {
    if (t >= KT) return;
    const int k0 = t << 6;
    u16* base = &As[t & 1][half][0];
#pragma unroll
    for (int i = 0; i < 2; ++i) {
      int q = i * 512 + tid;
      int r = q >> 3;
      int c8 = (q & 7) ^ (r & 7);
      GLD_TO_LDS16(A + (arow0 + half * 128 + r) * K + k0 + c8 * 8, base + q * 8);
    }
  };
  auto stageB = [&](int t, int half) {
    if (t >= KT) return;
    const int k0 = t << 6;
    u16* base = &Bs[t & 1][half][0];
#pragma unroll
    for (int i = 0; i < 2; ++i) {
      int q = i * 512 + tid;
      int r = q >> 3;
      int c8 = (q & 7) ^ (r & 7);
      GLD_TO_LDS16(Bw + (brow0 + half * 128 + r) * K + k0 + c8 * 8, base + q * 8);
    }
  };

  f32x4 acc[8][4] = {};
  bf16x8 aF[2][4], bF0[2][2], bF1[2][2];

  // ---- prologue: tile0 all 4 half-tiles + tile1 {A-h0, B-h0} (12 gl_lds);
  // vmcnt(4) drains tile0 (8), leaves tile1's h0 pair in flight.
  stageA(0, 0); stageB(0, 0); stageA(0, 1); stageB(0, 1);
  stageA(1, 0); stageB(1, 0);
  asm volatile("s_waitcnt vmcnt(4)" ::: "memory");
  __builtin_amdgcn_s_barrier();
  __builtin_amdgcn_sched_barrier(0);

  for (int t = 0; t < KT; ++t) {
    const int buf = t & 1;
    const u16* Ah0 = &As[buf][0][0];
    const u16* Ah1 = &As[buf][1][0];
    const u16* Bh0 = &Bs[buf][0][0];
    const u16* Bh1 = &Bs[buf][1][0];

    // ---- P1: (0,0) — reads A-mq0 + B-nq0; stage A(t+1)h1 ----
    fill_aq(aF, Ah0, wr, lane);
    fill_bq(bF0, Bh0, wn, lane);
    stageA(t + 1, 1);
    __builtin_amdgcn_s_barrier();
    LGKM0();
    MFMA16(0, 0, aF, bF0);
    __builtin_amdgcn_s_barrier();

    // ---- P2: (0,1) — reads B-nq1; stage B(t+1)h1 ----
    fill_bq(bF1, Bh1, wn, lane);
    stageB(t + 1, 1);
    __builtin_amdgcn_s_barrier();
    LGKM0();
    MFMA16(0, 1, aF, bF1);
    __builtin_amdgcn_s_barrier();

    // ---- P3: (1,0) — reads A-mq1; stage A(t+2)h0 ----
    fill_aq(aF, Ah1, wr, lane);
    stageA(t + 2, 0);
    __builtin_amdgcn_s_barrier();
    LGKM0();
    MFMA16(1, 0, aF, bF0);
    __builtin_amdgcn_s_barrier();

    // ---- P4: (1,1) — no reads; stage B(t+2)h0; counted vmcnt ----
    stageB(t + 2, 0);
    if (t >= KT - 2) asm volatile("s_waitcnt vmcnt(0)" ::: "memory");
    else             asm volatile("s_waitcnt vmcnt(4)" ::: "memory");
    __builtin_amdgcn_s_barrier();
    __builtin_amdgcn_sched_barrier(0);
    MFMA16(1, 1, aF, bF1);
    __builtin_amdgcn_s_barrier();
  }

  // ---- epilogue (optional fused RoPE for Q/K projections) ----
#pragma unroll
  for (int mi = 0; mi < 8; ++mi) {
    const int mq = mi >> 2, m = mi & 3;
#pragma unroll
    for (int ni = 0; ni < 4; ++ni) {
      const int nq = ni >> 1, n = ni & 1;
#pragma unroll
      for (int r = 0; r < 4; ++r) {
        size_t row = arow0 + mq * 128 + wr * 64 + m * 16 + ((lane >> 4) << 2) + r;
        size_t col = (size_t)tc * 256 + nq * 128 + wn * 32 + n * 16 + (lane & 15);
        float v = acc[mi][ni][r];
        if constexpr (ROPE) {
          float o = __shfl_xor(v, 1);                       // partner (col^1), same row
          int s = (int)(row & (S_ - 1));
          int p = (wn * 32 + n * 16 + (lane & 14)) >> 1;    // (col&127)>>1
          float cv = fc[(s << 6) + p];
          float sv = fs[(s << 6) + p];
          v = (lane & 1) ? (v * cv + o * sv) : (v * cv - o * sv);
        }
        if constexpr (__is_same(OutT, float)) {
          C[row * N + col] = v;
        } else {
          C[row * N + col] = f2bf(v);
        }
      }
    }
  }
}

// ---------------- Flash attention v9 (causal): uniform-work, NO setprio ----------
// r25-verified (134 us): 256 blocks, complementary q-supertiles (uniform 36
// kv-tiles), KVB=64, swapped-operand 32x32 MFMA, in-register softmax with
// prescaled Q, tree reductions, defer-max, no setprio.
__global__ __launch_bounds__(512, 2) void attn_kernel(const u16* __restrict__ Q,
                                                      const u16* __restrict__ K,
                                                      const u16* __restrict__ V,
                                                      u16* __restrict__ O) {
  __shared__ u16 Ks[2][64 * 128];   // [kv][d], chunk-XOR swizzled (cc ^= row&7)
  __shared__ u16 Vt[2][128 * 64];   // [d][kv], chunk-XOR swizzled (kvchunk ^= d&7)

  const int blk = blockIdx.x;
  const int pr = blk >> 6;          // 0..3 (complementary pair index)
  const int bh = blk & 63;
  const int b = bh >> 5, h = bh & 31;
  const int tid = threadIdx.x, lane = tid & 63, w = tid >> 6;
  const int l31 = lane & 31;
  const int hi = lane >> 5;               // 0/1 k-half
  const int r0 = lane >> 1;               // 0..31
  const int dc = 2 * w + (lane & 1);      // 0..15
  const int vd0 = dc * 8;

  for (int ph = 0; ph < 2; ++ph) {
    const int qt = ph == 0 ? 7 - pr : pr;   // pair sums to 36 tiles
    const int q0 = qt << 8;                 // 256 q-rows per phase
    const int wq0 = q0 + w * 32;
    const int qg = wq0 + l31;               // this lane's q row

    // Q frags, prescaled by C2_ (softmax scale folded in; one extra bf16 rounding)
    bf16x8 qf[8];
#pragma unroll
    for (int kb = 0; kb < 8; ++kb) {
      u16x8 qr = *reinterpret_cast<const u16x8*>(Q + (size_t)(b * S_ + qg) * D_ + h * HD_ + kb * 16 + hi * 8);
      u16x8 qs;
#pragma unroll
      for (int j = 0; j < 8; ++j) qs[j] = f2bf(bf2f(qr[j]) * C2_);
      qf[kb] = __builtin_bit_cast(bf16x8, qs);
    }

    f32x16 oacc[4] = {};   // O^T[dblock]: col=q(lane), row=d
    float mrun = -__builtin_inff(), lrun = 0.f;

    const int ntiles = 4 * qt + 4;
    u16x8 vr0, vr1;

    {
#pragma unroll
      for (int it = 0; it < 2; ++it) {
        int ff = it * 512 + tid;
        int row = ff >> 4, cc = ff & 15;
        int scc = cc ^ (row & 7);
        GLD_TO_LDS16(K + (size_t)(b * S_ + row) * D_ + h * HD_ + scc * 8, &Ks[0][ff << 3]);
      }
      vr0 = *reinterpret_cast<const u16x8*>(V + (size_t)(b * S_ + 2 * r0) * D_ + h * HD_ + vd0);
      vr1 = *reinterpret_cast<const u16x8*>(V + (size_t)(b * S_ + 2 * r0 + 1) * D_ + h * HD_ + vd0);
      u32* vt32 = reinterpret_cast<u32*>(&Vt[0][0]);
#pragma unroll
      for (int j = 0; j < 8; ++j) {
        int d = vd0 + j;
        u32 val = (u32)vr0[j] | ((u32)vr1[j] << 16);
        vt32[d * 32 + ((r0 >> 2) ^ j) * 4 + (r0 & 3)] = val;
      }
    }
    __syncthreads();

    for (int t = 0; t < ntiles; ++t) {
      const int cur = t & 1, nxt = cur ^ 1;
      const bool pre = (t + 1 < ntiles);
      if (pre) {
        const int kv1 = (t + 1) << 6;
#pragma unroll
        for (int it = 0; it < 2; ++it) {
          int ff = it * 512 + tid;
          int row = ff >> 4, cc = ff & 15;
          int scc = cc ^ (row & 7);
          GLD_TO_LDS16(K + (size_t)(b * S_ + kv1 + row) * D_ + h * HD_ + scc * 8, &Ks[nxt][ff << 3]);
        }
        vr0 = *reinterpret_cast<const u16x8*>(V + (size_t)(b * S_ + kv1 + 2 * r0) * D_ + h * HD_ + vd0);
        vr1 = *reinterpret_cast<const u16x8*>(V + (size_t)(b * S_ + kv1 + 2 * r0 + 1) * D_ + h * HD_ + vd0);
      }

      const int kv0 = t << 6;
      if (kv0 <= wq0 + 31) {  // wave-uniform causal skip
        f32x16 st[2] = {};
#pragma unroll
        for (int kvh = 0; kvh < 2; ++kvh) {
#pragma unroll
          for (int kb = 0; kb < 8; ++kb) {
            int row = kvh * 32 + l31;
            int cc = (2 * kb + hi) ^ (row & 7);
            bf16x8 kf = *reinterpret_cast<const bf16x8*>(&Ks[cur][(row << 7) + (cc << 3)]);
            st[kvh] = __builtin_amdgcn_mfma_f32_32x32x16_bf16(kf, qf[kb], st[kvh], 0, 0, 0);
          }
        }

        if (kv0 + 63 > wq0) {
#pragma unroll
          for (int kvh = 0; kvh < 2; ++kvh)
#pragma unroll
            for (int r = 0; r < 16; ++r) {
              int kvg = kv0 + kvh * 32 + (r & 3) + 8 * (r >> 2) + 4 * hi;
              if (kvg > qg) st[kvh][r] = -1e30f;
            }
        }

        // ---- tree max over 32 lane-local values + cross-half exchange ----
        float mx[8];
#pragma unroll
        for (int i = 0; i < 8; ++i)
          mx[i] = fmaxf(fmaxf(st[0][i], st[0][i + 8]), fmaxf(st[1][i], st[1][i + 8]));
#pragma unroll
        for (int i = 0; i < 4; ++i) mx[i] = fmaxf(mx[i], mx[i + 4]);
        float vmax = fmaxf(fmaxf(mx[0], mx[1]), fmaxf(mx[2], mx[3]));
        vmax = fmaxf(vmax, __shfl_xor(vmax, 32));
        // defer-max: rescale only when some row's max grew by > THR_ (scaled units)
        if (!__all(vmax <= mrun + THR_)) {
          float mnew = fmaxf(mrun, vmax);
          float sc = exp2f(mrun - mnew);
          mrun = mnew;
          lrun *= sc;
#pragma unroll
          for (int db = 0; db < 4; ++db)
#pragma unroll
            for (int r = 0; r < 16; ++r) oacc[db][r] *= sc;
        }
        // ---- exp (arg already scaled) + tree sum ----
        float ps[8];
#pragma unroll
        for (int kvh = 0; kvh < 2; ++kvh)
#pragma unroll
          for (int r = 0; r < 16; ++r) st[kvh][r] = exp2f(st[kvh][r] - mrun);
#pragma unroll
        for (int i = 0; i < 8; ++i)
          ps[i] = (st[0][i] + st[0][i + 8]) + (st[1][i] + st[1][i + 8]);
#pragma unroll
        for (int i = 0; i < 4; ++i) ps[i] += ps[i + 4];
        float psum = (ps[0] + ps[1]) + (ps[2] + ps[3]);
        psum += __shfl_xor(psum, 32);
        lrun += psum;

#pragma unroll
        for (int h2 = 0; h2 < 2; ++h2)
#pragma unroll
          for (int s2 = 0; s2 < 2; ++s2) {
            const int rb = s2 * 8;
            u32 w0, w1, w2, w3;
            asm("v_cvt_pk_bf16_f32 %0, %1, %2" : "=v"(w0) : "v"(st[h2][rb + 0]), "v"(st[h2][rb + 1]));
            asm("v_cvt_pk_bf16_f32 %0, %1, %2" : "=v"(w1) : "v"(st[h2][rb + 2]), "v"(st[h2][rb + 3]));
            asm("v_cvt_pk_bf16_f32 %0, %1, %2" : "=v"(w2) : "v"(st[h2][rb + 4]), "v"(st[h2][rb + 5]));
            asm("v_cvt_pk_bf16_f32 %0, %1, %2" : "=v"(w3) : "v"(st[h2][rb + 6]), "v"(st[h2][rb + 7]));
            u32 sw0 = (u32)__shfl_xor((int)w0, 32);
            u32 sw1 = (u32)__shfl_xor((int)w1, 32);
            u32 sw2 = (u32)__shfl_xor((int)w2, 32);
            u32 sw3 = (u32)__shfl_xor((int)w3, 32);
            u32x4 fw;
            fw[0] = hi ? sw2 : w0;
            fw[1] = hi ? sw3 : w1;
            fw[2] = hi ? w2 : sw0;
            fw[3] = hi ? w3 : sw1;
            bf16x8 pfrag = __builtin_bit_cast(bf16x8, fw);
#pragma unroll
            for (int db = 0; db < 4; ++db) {
              int d = db * 32 + l31;
              int cc = (h2 * 4 + s2 * 2 + hi) ^ (d & 7);
              bf16x8 va = *reinterpret_cast<const bf16x8*>(&Vt[cur][(d << 6) + (cc << 3)]);
              oacc[db] = __builtin_amdgcn_mfma_f32_32x32x16_bf16(va, pfrag, oacc[db], 0, 0, 0);
            }
          }
      }

      if (pre) {
        u32* vt32 = reinterpret_cast<u32*>(&Vt[nxt][0]);
#pragma unroll
        for (int j = 0; j < 8; ++j) {
          int d = vd0 + j;
          u32 val = (u32)vr0[j] | ((u32)vr1[j] << 16);
          vt32[d * 32 + ((r0 >> 2) ^ j) * 4 + (r0 & 3)] = val;
        }
      }
      __syncthreads();
    }

    // ---- phase epilogue: O[q][d] = oacc^T / lrun ----
    const float rinv = 1.0f / lrun;
#pragma unroll
    for (int db = 0; db < 4; ++db)
#pragma unroll
      for (int g = 0; g < 4; ++g) {
        u16x4 o4;
#pragma unroll
        for (int j = 0; j < 4; ++j) o4[j] = f2bf(oacc[db][g * 4 + j] * rinv);
        int d = db * 32 + g * 8 + 4 * hi;
        *reinterpret_cast<u16x4*>(O + (size_t)(b * S_ + qg) * D_ + h * HD_ + d) = o4;
      }
  }
}

// ---------------- launcher ----------------
extern "C" void kernel_launch(void* const* d_in, const int* in_sizes, int n_in,
                              void* d_out, int out_size, void* d_ws, size_t ws_size,
                              hipStream_t stream) {
  const float* x = (const float*)d_in[0];
  const float* wq = (const float*)d_in[1];
  const float* wk = (const float*)d_in[2];
  const float* wv = (const float*)d_in[3];
  const float* wo = (const float*)d_in[4];
  const float* fc = (const float*)d_in[5];
  const float* fs = (const float*)d_in[6];
  float* out = (float*)d_out;

  const size_t SLOT = (size_t)B_ * S_ * D_;  // 16,777,216 elements
  u16* ws = (u16*)d_ws;
  u16* wqb = ws + 0 * SLOT;
  u16* wkb = ws + 1 * SLOT;
  u16* wvb = ws + 2 * SLOT;
  u16* wob = ws + 3 * SLOT;
  u16* xb  = ws + 4 * SLOT;  // reused as attention output O after QKV GEMMs
  u16* Qb  = ws + 5 * SLOT;
  u16* Kb  = ws + 6 * SLOT;
  u16* Vb  = ws + 7 * SLOT;
  u16* Ob  = xb;

  const int n4 = (int)(SLOT / 4);
  cvt5_kernel<<<2560, 256, 0, stream>>>(x, wq, wk, wv, wo, xb, wqb, wkb, wvb, wob, n4);

  gemm256_kernel<u16, true><<<256, 512, 0, stream>>>(xb, wqb, Qb, B_ * S_, D_, D_, fc, fs);
  gemm256_kernel<u16, true><<<256, 512, 0, stream>>>(xb, wkb, Kb, B_ * S_, D_, D_, fc, fs);
  gemm256_kernel<u16, false><<<256, 512, 0, stream>>>(xb, wvb, Vb, B_ * S_, D_, D_, fc, fs);

  attn_kernel<<<256, 512, 0, stream>>>(Qb, Kb, Vb, Ob);

  gemm256_kernel<float, false><<<256, 512, 0, stream>>>(Ob, wob, out, B_ * S_, D_, D_, fc, fs);
}